// Round 1
// baseline (1884.586 us; speedup 1.0000x reference)
//
#include <hip/hip_runtime.h>

#define T_TOK 1024
#define D_HID 2048
#define NEXP 32
#define I_EXP 1408
#define TOPK 6
#define NGRP 8
#define GSIZE 4
#define TOPG 3
#define SHI 2816
#define RSCALE 2.5f

typedef __attribute__((ext_vector_type(8))) short short8;
typedef __attribute__((ext_vector_type(4))) float floatx4;

__device__ inline unsigned short f2b(float f) {
  unsigned int u = __float_as_uint(f);
  u += 0x7fffu + ((u >> 16) & 1u);   // round-to-nearest-even
  return (unsigned short)(u >> 16);
}

// ---------------- routing: one block (1 wave) per token ----------------
__global__ __launch_bounds__(64) void k_route(
    const float* __restrict__ x, const float* __restrict__ gw,
    const float* __restrict__ bias, int* __restrict__ tki, float* __restrict__ tkw)
{
  int t = blockIdx.x;
  __shared__ float xs[D_HID];
  __shared__ float sc[NEXP], cor[NEXP];
  int lane = threadIdx.x;
  for (int d = lane * 4; d < D_HID; d += 64 * 4)
    *(float4*)(xs + d) = *(const float4*)(x + (size_t)t * D_HID + d);
  __syncthreads();
  if (lane < NEXP) {
    float acc = 0.f;
    for (int d = 0; d < D_HID; ++d) acc += xs[d] * gw[d * NEXP + lane];
    float s = 1.f / (1.f + expf(-acc));
    sc[lane] = s;
    cor[lane] = s + bias[lane];
  }
  __syncthreads();
  if (lane == 0) {
    float gs[NGRP];
    for (int g = 0; g < NGRP; ++g) {
      float m1 = -INFINITY, m2 = -INFINITY;
      for (int j = 0; j < GSIZE; ++j) {
        float v = cor[g * GSIZE + j];
        if (v > m1) { m2 = m1; m1 = v; } else if (v > m2) m2 = v;
      }
      gs[g] = m1 + m2;
    }
    unsigned gmask = 0;
    for (int r = 0; r < TOPG; ++r) {
      int bi = -1; float bv = -INFINITY;
      for (int g = 0; g < NGRP; ++g)
        if (!((gmask >> g) & 1) && gs[g] > bv) { bv = gs[g]; bi = g; }
      gmask |= 1u << bi;
    }
    unsigned used = 0;
    float wsum = 0.f;
    int idxs[TOPK]; float wsel[TOPK];
    for (int r = 0; r < TOPK; ++r) {
      int bi = -1; float bv = -INFINITY;
      for (int e = 0; e < NEXP; ++e) {
        if (!((gmask >> (e / GSIZE)) & 1)) continue;
        if ((used >> e) & 1) continue;
        if (cor[e] > bv) { bv = cor[e]; bi = e; }
      }
      used |= 1u << bi;
      idxs[r] = bi; wsel[r] = sc[bi]; wsum += sc[bi];
    }
    float inv = 1.f / (wsum + 1e-20f);
    for (int r = 0; r < TOPK; ++r) {
      tki[t * TOPK + r] = idxs[r];
      tkw[t * TOPK + r] = wsel[r] * inv;
    }
  }
}

// ---------------- counts + offsets (single block) ----------------
__global__ __launch_bounds__(256) void k_count(const int* __restrict__ tki,
                                               int* __restrict__ cnt, int* __restrict__ offp)
{
  __shared__ int c[NEXP];
  if (threadIdx.x < NEXP) c[threadIdx.x] = 0;
  __syncthreads();
  for (int i = threadIdx.x; i < T_TOK * TOPK; i += 256) atomicAdd(&c[tki[i]], 1);
  __syncthreads();
  if (threadIdx.x == 0) {
    int s = 0;
    for (int e = 0; e < NEXP; ++e) { offp[e] = s; cnt[e] = c[e]; s += c[e]; }
    offp[NEXP] = s;
  }
}

// ---------------- deterministic compaction: one wave per expert ----------------
__global__ __launch_bounds__(64) void k_compact(
    const int* __restrict__ tki, const float* __restrict__ tkw,
    const int* __restrict__ offp, int* __restrict__ tok, float* __restrict__ wts)
{
  int e = blockIdx.x, lane = threadIdx.x;
  int base = offp[e];
  for (int t0 = 0; t0 < T_TOK; t0 += 64) {
    int t = t0 + lane;
    int found = -1;
    for (int j = 0; j < TOPK; ++j)
      if (tki[t * TOPK + j] == e) found = j;
    unsigned long long m = __ballot(found >= 0);
    if (found >= 0) {
      int pos = base + __popcll(m & ((1ull << lane) - 1ull));
      tok[pos] = t;
      wts[pos] = tkw[t * TOPK + found];
    }
    base += __popcll(m);
  }
}

// ---------------- fp32 -> bf16 cast of hidden states ----------------
__global__ __launch_bounds__(256) void k_cast(const float* __restrict__ x,
                                              unsigned short* __restrict__ xb, int n4)
{
  int i = blockIdx.x * 256 + threadIdx.x;
  if (i < n4) {
    float4 v = ((const float4*)x)[i];
    ushort4 o;
    o.x = f2b(v.x); o.y = f2b(v.y); o.z = f2b(v.z); o.w = f2b(v.w);
    ((ushort4*)xb)[i] = o;
  }
}

// ---------------- fused gate+up+silu grouped GEMM, 64x64 tile ----------------
__global__ __launch_bounds__(256) void k_gateup(
    const unsigned short* __restrict__ xb,
    const float* __restrict__ wg_base, const float* __restrict__ wu_base,
    const int* __restrict__ offp, const int* __restrict__ cntp,
    const int* __restrict__ toklist,
    unsigned short* __restrict__ hout,
    int Icols, int Dk, int denseRows)
{
  int e = blockIdx.z;
  int rowbase = offp ? offp[e] : 0;
  int nrows   = cntp ? cntp[e] : denseRows;
  int m0 = blockIdx.x * 64;
  if (m0 >= nrows) return;
  int n0 = blockIdx.y * 64;

  const float* wg = wg_base + (size_t)e * Dk * Icols;
  const float* wu = wu_base + (size_t)e * Dk * Icols;

  __shared__ __align__(16) unsigned short As[64][40];
  __shared__ __align__(16) unsigned short Bg[64][40];
  __shared__ __align__(16) unsigned short Bu[64][40];

  int tid = threadIdx.x;
  int wid = tid >> 6, lane = tid & 63;

  int ar = tid >> 2;
  int akk = (tid & 3) * 8;
  int arow = m0 + ar;
  int atok = 0;
  if (arow < nrows) atok = toklist ? toklist[rowbase + arow] : arow;
  const unsigned short* aptr = xb + (size_t)atok * Dk + akk;

  int bn = tid & 63;
  int bkk = (tid >> 6) * 8;

  floatx4 accg[4] = {};
  floatx4 accu[4] = {};

  for (int k0 = 0; k0 < Dk; k0 += 32) {
    *(uint4*)(&As[ar][akk]) = *(const uint4*)(aptr + k0);

    const float* gp = wg + (size_t)(k0 + bkk) * Icols + (n0 + bn);
    const float* up = wu + (size_t)(k0 + bkk) * Icols + (n0 + bn);
    alignas(16) unsigned short gt[8];
    alignas(16) unsigned short ut[8];
    #pragma unroll
    for (int i = 0; i < 8; ++i) {
      gt[i] = f2b(gp[(size_t)i * Icols]);
      ut[i] = f2b(up[(size_t)i * Icols]);
    }
    *(uint4*)(&Bg[bn][bkk]) = *(const uint4*)gt;
    *(uint4*)(&Bu[bn][bkk]) = *(const uint4*)ut;

    __syncthreads();
    short8 a = *(const short8*)(&As[wid * 16 + (lane & 15)][(lane >> 4) * 8]);
    #pragma unroll
    for (int nf = 0; nf < 4; ++nf) {
      short8 bg = *(const short8*)(&Bg[nf * 16 + (lane & 15)][(lane >> 4) * 8]);
      accg[nf] = __builtin_amdgcn_mfma_f32_16x16x32_bf16(a, bg, accg[nf], 0, 0, 0);
    }
    #pragma unroll
    for (int nf = 0; nf < 4; ++nf) {
      short8 bu = *(const short8*)(&Bu[nf * 16 + (lane & 15)][(lane >> 4) * 8]);
      accu[nf] = __builtin_amdgcn_mfma_f32_16x16x32_bf16(a, bu, accu[nf], 0, 0, 0);
    }
    __syncthreads();
  }

  #pragma unroll
  for (int nf = 0; nf < 4; ++nf) {
    #pragma unroll
    for (int v = 0; v < 4; ++v) {
      int r = wid * 16 + (lane >> 4) * 4 + v;
      if (m0 + r < nrows) {
        float g = accg[nf][v], u = accu[nf][v];
        float s = 1.0f / (1.0f + __expf(-g));
        hout[(size_t)(rowbase + m0 + r) * Icols + (n0 + nf * 16 + (lane & 15))] = f2b(g * s * u);
      }
    }
  }
}

// ---------------- down-proj grouped GEMM + weighted scatter-add ----------------
__global__ __launch_bounds__(256) void k_down(
    const unsigned short* __restrict__ hin,
    const float* __restrict__ wd_base,
    const int* __restrict__ offp, const int* __restrict__ cntp,
    const int* __restrict__ toklist, const float* __restrict__ wt,
    float* __restrict__ out,
    int Icols, int Dcols, int denseRows, float scale)
{
  int e = blockIdx.z;
  int rowbase = offp ? offp[e] : 0;
  int nrows   = cntp ? cntp[e] : denseRows;
  int m0 = blockIdx.x * 64;
  if (m0 >= nrows) return;
  int n0 = blockIdx.y * 64;
  const float* wd = wd_base + (size_t)e * Icols * Dcols;

  __shared__ __align__(16) unsigned short As[64][40];
  __shared__ __align__(16) unsigned short Bd[64][40];

  int tid = threadIdx.x, wid = tid >> 6, lane = tid & 63;
  int ar = tid >> 2, akk = (tid & 3) * 8;
  int srcrow = (m0 + ar < nrows) ? (rowbase + m0 + ar) : rowbase;
  const unsigned short* aptr = hin + (size_t)srcrow * Icols + akk;
  int bn = tid & 63, bkk = (tid >> 6) * 8;

  floatx4 acc[4] = {};

  for (int k0 = 0; k0 < Icols; k0 += 32) {
    *(uint4*)(&As[ar][akk]) = *(const uint4*)(aptr + k0);
    const float* dp = wd + (size_t)(k0 + bkk) * Dcols + (n0 + bn);
    alignas(16) unsigned short dt[8];
    #pragma unroll
    for (int i = 0; i < 8; ++i) dt[i] = f2b(dp[(size_t)i * Dcols]);
    *(uint4*)(&Bd[bn][bkk]) = *(const uint4*)dt;
    __syncthreads();
    short8 a = *(const short8*)(&As[wid * 16 + (lane & 15)][(lane >> 4) * 8]);
    #pragma unroll
    for (int nf = 0; nf < 4; ++nf) {
      short8 b = *(const short8*)(&Bd[nf * 16 + (lane & 15)][(lane >> 4) * 8]);
      acc[nf] = __builtin_amdgcn_mfma_f32_16x16x32_bf16(a, b, acc[nf], 0, 0, 0);
    }
    __syncthreads();
  }

  #pragma unroll
  for (int nf = 0; nf < 4; ++nf) {
    #pragma unroll
    for (int v = 0; v < 4; ++v) {
      int r = wid * 16 + (lane >> 4) * 4 + v;
      if (m0 + r < nrows) {
        int grow = rowbase + m0 + r;
        int tk = toklist ? toklist[grow] : (m0 + r);
        float w = wt ? wt[grow] * scale : scale;
        atomicAdd(&out[(size_t)tk * Dcols + (n0 + nf * 16 + (lane & 15))], w * acc[nf][v]);
      }
    }
  }
}

extern "C" void kernel_launch(void* const* d_in, const int* in_sizes, int n_in,
                              void* d_out, int out_size, void* d_ws, size_t ws_size,
                              hipStream_t stream) {
  const float* x    = (const float*)d_in[0];
  const float* gw   = (const float*)d_in[1];
  const float* bias = (const float*)d_in[2];
  const float* wg   = (const float*)d_in[3];
  const float* wu   = (const float*)d_in[4];
  const float* wd   = (const float*)d_in[5];
  const float* wsg  = (const float*)d_in[6];
  const float* wsu  = (const float*)d_in[7];
  const float* wsd  = (const float*)d_in[8];
  float* out = (float*)d_out;

  char* ws = (char*)d_ws;
  size_t o = 0;
  auto take = [&](size_t bytes) {
    char* p = ws + o;
    o += (bytes + 255) & ~(size_t)255;
    return p;
  };
  int*   tki  = (int*)  take((size_t)T_TOK * TOPK * 4);
  float* tkw  = (float*)take((size_t)T_TOK * TOPK * 4);
  int*   cnt  = (int*)  take(NEXP * 4);
  int*   offp = (int*)  take((NEXP + 1) * 4);
  int*   tok  = (int*)  take((size_t)T_TOK * TOPK * 4);
  float* wts  = (float*)take((size_t)T_TOK * TOPK * 4);
  unsigned short* xb = (unsigned short*)take((size_t)T_TOK * D_HID * 2);
  unsigned short* hb = (unsigned short*)take((size_t)T_TOK * TOPK * I_EXP * 2);
  unsigned short* sh = (unsigned short*)take((size_t)T_TOK * SHI * 2);

  hipMemsetAsync(d_out, 0, (size_t)T_TOK * D_HID * sizeof(float), stream);
  k_route<<<T_TOK, 64, 0, stream>>>(x, gw, bias, tki, tkw);
  k_count<<<1, 256, 0, stream>>>(tki, cnt, offp);
  k_compact<<<NEXP, 64, 0, stream>>>(tki, tkw, offp, tok, wts);
  k_cast<<<(T_TOK * D_HID / 4 + 255) / 256, 256, 0, stream>>>(x, xb, T_TOK * D_HID / 4);

  // routed experts
  k_gateup<<<dim3(T_TOK / 64, I_EXP / 64, NEXP), 256, 0, stream>>>(
      xb, wg, wu, offp, cnt, tok, hb, I_EXP, D_HID, 0);
  // shared expert (dense)
  k_gateup<<<dim3(T_TOK / 64, SHI / 64, 1), 256, 0, stream>>>(
      xb, wsg, wsu, nullptr, nullptr, nullptr, sh, SHI, D_HID, T_TOK);
  // routed down + scatter
  k_down<<<dim3(T_TOK / 64, D_HID / 64, NEXP), 256, 0, stream>>>(
      hb, wd, offp, cnt, tok, wts, out, I_EXP, D_HID, 0, RSCALE);
  // shared down
  k_down<<<dim3(T_TOK / 64, D_HID / 64, 1), 256, 0, stream>>>(
      sh, wsd, nullptr, nullptr, nullptr, nullptr, out, SHI, D_HID, T_TOK, 1.0f);
}

// Round 2
// 910.555 us; speedup vs baseline: 2.0697x; 2.0697x over previous
//
#include <hip/hip_runtime.h>

#define T_TOK 1024
#define D_HID 2048
#define NEXP 32
#define I_EXP 1408
#define TOPK 6
#define NGRP 8
#define GSIZE 4
#define TOPG 3
#define SHI 2816
#define RSCALE 2.5f

typedef __attribute__((ext_vector_type(8))) short short8;
typedef __attribute__((ext_vector_type(4))) float floatx4;

__device__ __forceinline__ unsigned short f2b(float f) {
  unsigned int u = __float_as_uint(f);
  u += 0x7fffu + ((u >> 16) & 1u);   // RNE
  return (unsigned short)(u >> 16);
}

__device__ __forceinline__ void gld_lds16(const void* g, void* l) {
  __builtin_amdgcn_global_load_lds(
      (const __attribute__((address_space(1))) unsigned int*)g,
      (__attribute__((address_space(3))) unsigned int*)l, 16, 0, 0);
}

// ---------------- routing: one block (1 wave) per token ----------------
__global__ __launch_bounds__(64) void k_route(
    const float* __restrict__ x, const float* __restrict__ gw,
    const float* __restrict__ bias, int* __restrict__ tki, float* __restrict__ tkw)
{
  int t = blockIdx.x;
  __shared__ float xs[D_HID];
  __shared__ float sc[NEXP], cor[NEXP];
  int lane = threadIdx.x;
  for (int d = lane * 4; d < D_HID; d += 64 * 4)
    *(float4*)(xs + d) = *(const float4*)(x + (size_t)t * D_HID + d);
  __syncthreads();
  if (lane < NEXP) {
    float acc = 0.f;
    for (int d = 0; d < D_HID; ++d) acc += xs[d] * gw[d * NEXP + lane];
    float s = 1.f / (1.f + expf(-acc));
    sc[lane] = s;
    cor[lane] = s + bias[lane];
  }
  __syncthreads();
  if (lane == 0) {
    float gs[NGRP];
    for (int g = 0; g < NGRP; ++g) {
      float m1 = -INFINITY, m2 = -INFINITY;
      for (int j = 0; j < GSIZE; ++j) {
        float v = cor[g * GSIZE + j];
        if (v > m1) { m2 = m1; m1 = v; } else if (v > m2) m2 = v;
      }
      gs[g] = m1 + m2;
    }
    unsigned gmask = 0;
    for (int r = 0; r < TOPG; ++r) {
      int bi = -1; float bv = -INFINITY;
      for (int g = 0; g < NGRP; ++g)
        if (!((gmask >> g) & 1) && gs[g] > bv) { bv = gs[g]; bi = g; }
      gmask |= 1u << bi;
    }
    unsigned used = 0;
    float wsum = 0.f;
    int idxs[TOPK]; float wsel[TOPK];
    for (int r = 0; r < TOPK; ++r) {
      int bi = -1; float bv = -INFINITY;
      for (int e = 0; e < NEXP; ++e) {
        if (!((gmask >> (e / GSIZE)) & 1)) continue;
        if ((used >> e) & 1) continue;
        if (cor[e] > bv) { bv = cor[e]; bi = e; }
      }
      used |= 1u << bi;
      idxs[r] = bi; wsel[r] = sc[bi]; wsum += sc[bi];
    }
    float inv = 1.f / (wsum + 1e-20f);
    for (int r = 0; r < TOPK; ++r) {
      tki[t * TOPK + r] = idxs[r];
      tkw[t * TOPK + r] = wsel[r] * inv;
    }
  }
}

// ---------------- counts + offsets (single block) ----------------
__global__ __launch_bounds__(256) void k_count(const int* __restrict__ tki,
                                               int* __restrict__ cnt, int* __restrict__ offp)
{
  __shared__ int c[NEXP];
  if (threadIdx.x < NEXP) c[threadIdx.x] = 0;
  __syncthreads();
  for (int i = threadIdx.x; i < T_TOK * TOPK; i += 256) atomicAdd(&c[tki[i]], 1);
  __syncthreads();
  if (threadIdx.x == 0) {
    int s = 0;
    for (int e = 0; e < NEXP; ++e) { offp[e] = s; cnt[e] = c[e]; s += c[e]; }
    offp[NEXP] = s;
  }
}

// ---------------- deterministic compaction: one wave per expert ----------------
__global__ __launch_bounds__(64) void k_compact(
    const int* __restrict__ tki, const float* __restrict__ tkw,
    const int* __restrict__ offp, int* __restrict__ tok, float* __restrict__ wts)
{
  int e = blockIdx.x, lane = threadIdx.x;
  int base = offp[e];
  for (int t0 = 0; t0 < T_TOK; t0 += 64) {
    int t = t0 + lane;
    int found = -1;
    for (int j = 0; j < TOPK; ++j)
      if (tki[t * TOPK + j] == e) found = j;
    unsigned long long m = __ballot(found >= 0);
    if (found >= 0) {
      int pos = base + __popcll(m & ((1ull << lane) - 1ull));
      tok[pos] = t;
      wts[pos] = tkw[t * TOPK + found];
    }
    base += __popcll(m);
  }
}

// ---------------- fp32 -> bf16 cast of hidden states ----------------
__global__ __launch_bounds__(256) void k_cast(const float* __restrict__ x,
                                              unsigned short* __restrict__ xb, int n4)
{
  int i = blockIdx.x * 256 + threadIdx.x;
  if (i < n4) {
    float4 v = ((const float4*)x)[i];
    ushort4 o;
    o.x = f2b(v.x); o.y = f2b(v.y); o.z = f2b(v.z); o.w = f2b(v.w);
    ((ushort4*)xb)[i] = o;
  }
}

// =================================================================
// Gate+Up fused grouped GEMM.  Block: 512 thr (8 waves), tile 256m x 64n,
// BK=32, double-buffered LDS, 2-phase prefetch.  M handled by in-kernel loop
// (no dead blocks).  grid = (N/64, experts_or_mchunks)
// =================================================================
__global__ __launch_bounds__(512) void k_gateup2(
    const unsigned short* __restrict__ xb,
    const float* __restrict__ wg_base, const float* __restrict__ wu_base,
    const int* __restrict__ offp, const int* __restrict__ cnt,
    const int* __restrict__ tok,
    unsigned short* __restrict__ hout,
    int N, int K, int denseM)
{
  __shared__ __align__(16) unsigned short As[2][256 * 32];
  __shared__ __align__(16) unsigned short Bg[2][64][40];
  __shared__ __align__(16) unsigned short Bu[2][64][40];

  int tid = threadIdx.x;
  int wid = tid >> 6, lane = tid & 63;
  int n0 = blockIdx.x * 64;

  int e, rowbase, nrows;
  if (offp) { e = blockIdx.y; rowbase = offp[e]; nrows = cnt[e]; }
  else      { e = 0; rowbase = blockIdx.y * 256; nrows = 256; }

  const float* wg = wg_base + (size_t)e * K * N;
  const float* wu = wu_base + (size_t)e * K * N;

  // B staging mapping: thread -> (k row bkk, n-float4 bn4)
  int bn4 = tid & 15;
  int bkk = tid >> 4;                       // 0..31
  const float* gsrc = wg + (size_t)bkk * N + n0 + bn4 * 4;
  const float* usrc = wu + (size_t)bkk * N + n0 + bn4 * 4;

  // A staging mapping: 2 passes of 512x16B
  int rowA0 = tid >> 2;                     // 0..127
  int rowA1 = 128 + rowA0;
  int kkA = (tid & 3) * 8;
  int NK = K / 32;

  for (int m0 = 0; m0 < nrows; m0 += 256) {
    const unsigned short *ga0, *ga1;
    if (offp) {
      int tA0 = tok[rowbase + min(m0 + rowA0, nrows - 1)];
      int tA1 = tok[rowbase + min(m0 + rowA1, nrows - 1)];
      ga0 = xb + (size_t)tA0 * K + kkA;
      ga1 = xb + (size_t)tA1 * K + kkA;
    } else {
      ga0 = xb + (size_t)(rowbase + rowA0) * K + kkA;
      ga1 = xb + (size_t)(rowbase + rowA1) * K + kkA;
    }

    floatx4 accg[2][4] = {};
    floatx4 accu[2][4] = {};

    // prologue: stage tile 0 into buf 0
    gld_lds16(ga0, &As[0][tid * 8]);
    gld_lds16(ga1, &As[0][(512 + tid) * 8]);
    {
      float4 gr = *(const float4*)gsrc;
      float4 ur = *(const float4*)usrc;
      #pragma unroll
      for (int j = 0; j < 4; ++j) {
        Bg[0][bn4 * 4 + j][bkk] = f2b(((const float*)&gr)[j]);
        Bu[0][bn4 * 4 + j][bkk] = f2b(((const float*)&ur)[j]);
      }
    }
    __syncthreads();

    int b = 0;
    for (int kt = 0; kt < NK; ++kt) {
      float4 gr, ur;
      bool pre = (kt + 1 < NK);
      if (pre) {
        gld_lds16(ga0 + (kt + 1) * 32, &As[b ^ 1][tid * 8]);
        gld_lds16(ga1 + (kt + 1) * 32, &As[b ^ 1][(512 + tid) * 8]);
        gr = *(const float4*)(gsrc + (size_t)(kt + 1) * 32 * N);
        ur = *(const float4*)(usrc + (size_t)(kt + 1) * 32 * N);
      }
      // compute current buffer
      {
        short8 af0 = *(const short8*)&As[b][(wid * 32 + (lane & 15)) * 32 + (lane >> 4) * 8];
        short8 af1 = *(const short8*)&As[b][(wid * 32 + 16 + (lane & 15)) * 32 + (lane >> 4) * 8];
        #pragma unroll
        for (int nf = 0; nf < 4; ++nf) {
          short8 bg = *(const short8*)&Bg[b][nf * 16 + (lane & 15)][(lane >> 4) * 8];
          accg[0][nf] = __builtin_amdgcn_mfma_f32_16x16x32_bf16(af0, bg, accg[0][nf], 0, 0, 0);
          accg[1][nf] = __builtin_amdgcn_mfma_f32_16x16x32_bf16(af1, bg, accg[1][nf], 0, 0, 0);
          short8 bu = *(const short8*)&Bu[b][nf * 16 + (lane & 15)][(lane >> 4) * 8];
          accu[0][nf] = __builtin_amdgcn_mfma_f32_16x16x32_bf16(af0, bu, accu[0][nf], 0, 0, 0);
          accu[1][nf] = __builtin_amdgcn_mfma_f32_16x16x32_bf16(af1, bu, accu[1][nf], 0, 0, 0);
        }
      }
      if (pre) {
        #pragma unroll
        for (int j = 0; j < 4; ++j) {
          Bg[b ^ 1][bn4 * 4 + j][bkk] = f2b(((const float*)&gr)[j]);
          Bu[b ^ 1][bn4 * 4 + j][bkk] = f2b(((const float*)&ur)[j]);
        }
      }
      __syncthreads();
      b ^= 1;
    }

    // epilogue: silu(g)*u -> bf16
    #pragma unroll
    for (int mi = 0; mi < 2; ++mi)
      #pragma unroll
      for (int nf = 0; nf < 4; ++nf)
        #pragma unroll
        for (int v = 0; v < 4; ++v) {
          int r = wid * 32 + mi * 16 + (lane >> 4) * 4 + v;
          if (m0 + r < nrows) {
            float g = accg[mi][nf][v], u = accu[mi][nf][v];
            float s = g / (1.f + __expf(-g));
            hout[(size_t)(rowbase + m0 + r) * N + n0 + nf * 16 + (lane & 15)] = f2b(s * u);
          }
        }
  }
}

// =================================================================
// Down-proj grouped GEMM.  Same structure, single B mat.
// Routed: atomicAdd(w*scale*acc) scattered by token.  Dense: plain store.
// =================================================================
__global__ __launch_bounds__(512) void k_down2(
    const unsigned short* __restrict__ hin,
    const float* __restrict__ wd_base,
    const int* __restrict__ offp, const int* __restrict__ cnt,
    const int* __restrict__ tok, const float* __restrict__ wts,
    float* __restrict__ out,
    int N, int K, float scale)
{
  __shared__ __align__(16) unsigned short As[2][256 * 32];
  __shared__ __align__(16) unsigned short Bd[2][64][40];

  int tid = threadIdx.x;
  int wid = tid >> 6, lane = tid & 63;
  int n0 = blockIdx.x * 64;

  int e, rowbase, nrows;
  if (offp) { e = blockIdx.y; rowbase = offp[e]; nrows = cnt[e]; }
  else      { e = 0; rowbase = blockIdx.y * 256; nrows = 256; }

  const float* wd = wd_base + (size_t)e * K * N;

  int bn4 = tid & 15;
  int bkk = tid >> 4;
  const float* dsrc = wd + (size_t)bkk * N + n0 + bn4 * 4;

  int rowA0 = tid >> 2;
  int rowA1 = 128 + rowA0;
  int kkA = (tid & 3) * 8;
  int NK = K / 32;

  for (int m0 = 0; m0 < nrows; m0 += 256) {
    int rl0 = min(m0 + rowA0, nrows - 1);
    int rl1 = min(m0 + rowA1, nrows - 1);
    const unsigned short* ga0 = hin + (size_t)(rowbase + rl0) * K + kkA;
    const unsigned short* ga1 = hin + (size_t)(rowbase + rl1) * K + kkA;

    floatx4 acc[2][4] = {};

    gld_lds16(ga0, &As[0][tid * 8]);
    gld_lds16(ga1, &As[0][(512 + tid) * 8]);
    {
      float4 dr = *(const float4*)dsrc;
      #pragma unroll
      for (int j = 0; j < 4; ++j)
        Bd[0][bn4 * 4 + j][bkk] = f2b(((const float*)&dr)[j]);
    }
    __syncthreads();

    int b = 0;
    for (int kt = 0; kt < NK; ++kt) {
      float4 dr;
      bool pre = (kt + 1 < NK);
      if (pre) {
        gld_lds16(ga0 + (kt + 1) * 32, &As[b ^ 1][tid * 8]);
        gld_lds16(ga1 + (kt + 1) * 32, &As[b ^ 1][(512 + tid) * 8]);
        dr = *(const float4*)(dsrc + (size_t)(kt + 1) * 32 * N);
      }
      {
        short8 af0 = *(const short8*)&As[b][(wid * 32 + (lane & 15)) * 32 + (lane >> 4) * 8];
        short8 af1 = *(const short8*)&As[b][(wid * 32 + 16 + (lane & 15)) * 32 + (lane >> 4) * 8];
        #pragma unroll
        for (int nf = 0; nf < 4; ++nf) {
          short8 bd = *(const short8*)&Bd[b][nf * 16 + (lane & 15)][(lane >> 4) * 8];
          acc[0][nf] = __builtin_amdgcn_mfma_f32_16x16x32_bf16(af0, bd, acc[0][nf], 0, 0, 0);
          acc[1][nf] = __builtin_amdgcn_mfma_f32_16x16x32_bf16(af1, bd, acc[1][nf], 0, 0, 0);
        }
      }
      if (pre) {
        #pragma unroll
        for (int j = 0; j < 4; ++j)
          Bd[b ^ 1][bn4 * 4 + j][bkk] = f2b(((const float*)&dr)[j]);
      }
      __syncthreads();
      b ^= 1;
    }

    #pragma unroll
    for (int mi = 0; mi < 2; ++mi)
      #pragma unroll
      for (int nf = 0; nf < 4; ++nf)
        #pragma unroll
        for (int v = 0; v < 4; ++v) {
          int r = wid * 32 + mi * 16 + (lane >> 4) * 4 + v;
          if (m0 + r < nrows) {
            int grow = rowbase + m0 + r;
            int col = n0 + nf * 16 + (lane & 15);
            if (offp) {
              float w = wts[grow] * scale;
              atomicAdd(&out[(size_t)tok[grow] * N + col], w * acc[mi][nf][v]);
            } else {
              out[(size_t)grow * N + col] = acc[mi][nf][v] * scale;
            }
          }
        }
  }
}

extern "C" void kernel_launch(void* const* d_in, const int* in_sizes, int n_in,
                              void* d_out, int out_size, void* d_ws, size_t ws_size,
                              hipStream_t stream) {
  const float* x    = (const float*)d_in[0];
  const float* gw   = (const float*)d_in[1];
  const float* bias = (const float*)d_in[2];
  const float* wg   = (const float*)d_in[3];
  const float* wu   = (const float*)d_in[4];
  const float* wd   = (const float*)d_in[5];
  const float* wsg  = (const float*)d_in[6];
  const float* wsu  = (const float*)d_in[7];
  const float* wsd  = (const float*)d_in[8];
  float* out = (float*)d_out;

  char* ws = (char*)d_ws;
  size_t o = 0;
  auto take = [&](size_t bytes) {
    char* p = ws + o;
    o += (bytes + 255) & ~(size_t)255;
    return p;
  };
  int*   tki  = (int*)  take((size_t)T_TOK * TOPK * 4);
  float* tkw  = (float*)take((size_t)T_TOK * TOPK * 4);
  int*   cnt  = (int*)  take(NEXP * 4);
  int*   offp = (int*)  take((NEXP + 1) * 4);
  int*   tok  = (int*)  take((size_t)T_TOK * TOPK * 4);
  float* wts  = (float*)take((size_t)T_TOK * TOPK * 4);
  unsigned short* xb = (unsigned short*)take((size_t)T_TOK * D_HID * 2);
  unsigned short* hb = (unsigned short*)take((size_t)T_TOK * TOPK * I_EXP * 2);
  unsigned short* sh = (unsigned short*)take((size_t)T_TOK * SHI * 2);

  k_route<<<T_TOK, 64, 0, stream>>>(x, gw, bias, tki, tkw);
  k_count<<<1, 256, 0, stream>>>(tki, cnt, offp);
  k_compact<<<NEXP, 64, 0, stream>>>(tki, tkw, offp, tok, wts);
  k_cast<<<(T_TOK * D_HID / 4 + 255) / 256, 256, 0, stream>>>(x, xb, T_TOK * D_HID / 4);

  // shared expert gate+up (dense, 4 m-chunks)
  k_gateup2<<<dim3(SHI / 64, T_TOK / 256), 512, 0, stream>>>(
      xb, wsg, wsu, nullptr, nullptr, nullptr, sh, SHI, D_HID, T_TOK);
  // routed gate+up (grouped, in-kernel m loop)
  k_gateup2<<<dim3(I_EXP / 64, NEXP), 512, 0, stream>>>(
      xb, wg, wu, offp, cnt, tok, hb, I_EXP, D_HID, 0);
  // shared down: plain store (initializes out, replaces memset)
  k_down2<<<dim3(D_HID / 64, T_TOK / 256), 512, 0, stream>>>(
      sh, wsd, nullptr, nullptr, nullptr, nullptr, out, D_HID, SHI, 1.0f);
  // routed down: atomic accumulate on top
  k_down2<<<dim3(D_HID / 64, NEXP), 512, 0, stream>>>(
      hb, wd, offp, cnt, tok, wts, out, D_HID, I_EXP, RSCALE);
}